// Round 2
// baseline (10002.269 us; speedup 1.0000x reference)
//
#include <hip/hip_runtime.h>

// SparseMultiHeadAttention: B=4 S=2048 D=1024 H=16 DK=64 WINDOW=256 GLOBAL=16
// Round 2: attention rewritten — 64x64 tiles, 4x4 register tile per thread,
// Q hoisted to VGPRs, wave-shuffle softmax, 3 barriers per 64-key tile.
// GEMMs unchanged from round 1 (fp32 128x128x16 tiles).

#define B_   4
#define S_   2048
#define D_   1024
#define H_   16
#define DK_  64
#define WIN_ 256
#define GLB_ 16

// ---------------------------------------------------------------------------
// GEMM: C = A(8192x1024) @ W(1024x1024) + bias   (unchanged)
// ---------------------------------------------------------------------------
#define BM 128
#define BN 128
#define BK 16

__global__ __launch_bounds__(256, 2) void gemm_f32(
    const float* __restrict__ A, const float* __restrict__ W,
    const float* __restrict__ bias, float* __restrict__ C, int mode)
{
  __shared__ float As[BK][BM + 4];
  __shared__ float Bs[BK][BN + 4];
  const int tid = threadIdx.x;
  const int bm = blockIdx.y * BM;
  const int bn = blockIdx.x * BN;
  const int tx = tid & 15;
  const int ty = tid >> 4;
  const int K = 1024, N = 1024;

  float acc[8][8];
#pragma unroll
  for (int i = 0; i < 8; ++i)
#pragma unroll
    for (int j = 0; j < 8; ++j) acc[i][j] = 0.f;

  const int arow = tid >> 2;
  const int acol = (tid & 3) * 4;
  const int brow = tid >> 5;
  const int bcol = (tid & 31) * 4;

  for (int k0 = 0; k0 < K; k0 += BK) {
    float4 a0 = *(const float4*)(A + (size_t)(bm + arow) * K + k0 + acol);
    float4 a1 = *(const float4*)(A + (size_t)(bm + arow + 64) * K + k0 + acol);
    float4 b0 = *(const float4*)(W + (size_t)(k0 + brow) * N + bn + bcol);
    float4 b1 = *(const float4*)(W + (size_t)(k0 + brow + 8) * N + bn + bcol);
    __syncthreads();
    As[acol + 0][arow] = a0.x; As[acol + 1][arow] = a0.y;
    As[acol + 2][arow] = a0.z; As[acol + 3][arow] = a0.w;
    As[acol + 0][arow + 64] = a1.x; As[acol + 1][arow + 64] = a1.y;
    As[acol + 2][arow + 64] = a1.z; As[acol + 3][arow + 64] = a1.w;
    *(float4*)&Bs[brow][bcol]     = b0;
    *(float4*)&Bs[brow + 8][bcol] = b1;
    __syncthreads();
#pragma unroll
    for (int kk = 0; kk < BK; ++kk) {
      float a[8], b[8];
      float4 t;
      t = *(float4*)&As[kk][ty * 8];     a[0]=t.x; a[1]=t.y; a[2]=t.z; a[3]=t.w;
      t = *(float4*)&As[kk][ty * 8 + 4]; a[4]=t.x; a[5]=t.y; a[6]=t.z; a[7]=t.w;
      t = *(float4*)&Bs[kk][tx * 8];     b[0]=t.x; b[1]=t.y; b[2]=t.z; b[3]=t.w;
      t = *(float4*)&Bs[kk][tx * 8 + 4]; b[4]=t.x; b[5]=t.y; b[6]=t.z; b[7]=t.w;
#pragma unroll
      for (int i = 0; i < 8; ++i)
#pragma unroll
        for (int j = 0; j < 8; ++j)
          acc[i][j] = fmaf(a[i], b[j], acc[i][j]);
    }
  }

  const float4 bias0 = *(const float4*)(bias + bn + tx * 8);
  const float4 bias1 = *(const float4*)(bias + bn + tx * 8 + 4);
  if (mode == 0) {
#pragma unroll
    for (int i = 0; i < 8; ++i) {
      const int m = bm + ty * 8 + i;
      float* dst = C + (size_t)m * 1024 + bn + tx * 8;
      float4 o0 = make_float4(acc[i][0] + bias0.x, acc[i][1] + bias0.y,
                              acc[i][2] + bias0.z, acc[i][3] + bias0.w);
      float4 o1 = make_float4(acc[i][4] + bias1.x, acc[i][5] + bias1.y,
                              acc[i][6] + bias1.z, acc[i][7] + bias1.w);
      *(float4*)dst = o0; *(float4*)(dst + 4) = o1;
    }
  } else {
    const int ncol = bn + tx * 8;
    const int h  = ncol >> 6;
    const int dk = ncol & 63;
#pragma unroll
    for (int i = 0; i < 8; ++i) {
      const int m = bm + ty * 8 + i;
      const int bb = m >> 11;
      const int s  = m & 2047;
      float* dst = C + ((size_t)(bb * H_ + h) * S_ + s) * DK_ + dk;
      float4 o0 = make_float4(acc[i][0] + bias0.x, acc[i][1] + bias0.y,
                              acc[i][2] + bias0.z, acc[i][3] + bias0.w);
      float4 o1 = make_float4(acc[i][4] + bias1.x, acc[i][5] + bias1.y,
                              acc[i][6] + bias1.z, acc[i][7] + bias1.w);
      *(float4*)dst = o0; *(float4*)(dst + 4) = o1;
    }
  }
}

// ---------------------------------------------------------------------------
// Banded attention v2. Block = 256 threads (4 waves) = one (b,h,64-row Qtile).
// Thread (tr=tid>>4, tc=tid&15):
//   scores: rows tr*4..+3  x keys {tc, tc+16, tc+32, tc+48}
//   PV/out: rows tr*4..+3  x dims tc*4..+3
// Row softmax: a row's 16 threads are lanes (tr%4)*16 .. +15 of one wave
//   -> shfl_xor reduce over masks 1,2,4,8. No serial section.
// P handoff via transposed LDS tile Ps[key][row] (also reused for Q staging).
// ---------------------------------------------------------------------------
__global__ __launch_bounds__(256, 3) void attn_v2(
    const float* __restrict__ Qp, const float* __restrict__ Kp,
    const float* __restrict__ Vp, const float* __restrict__ amask,
    float* __restrict__ AO)
{
  __shared__ float Ks[64][68], Vs[64][68], Ps[64][68];   // 52,224 B

  const int tid = threadIdx.x;
  const int qt = blockIdx.x;   // 0..31
  const int h  = blockIdx.y;
  const int b  = blockIdx.z;
  const int i0 = qt * 64;
  const int tr = tid >> 4;     // 0..15 -> rows tr*4..tr*4+3
  const int tc = tid & 15;

  const size_t head_off = (size_t)(b * H_ + h) * S_ * DK_;
  const float* Qh = Qp + head_off;
  const float* Kh = Kp + head_off;
  const float* Vh = Vp + head_off;

  // ---- stage Q tile into Ps, then hoist this thread's 4 rows to VGPRs ----
#pragma unroll
  for (int r = 0; r < 4; ++r) {
    const int f = tid + r * 256;          // 1024 float4 slots
    const int row = f >> 4, col = (f & 15) * 4;
    *(float4*)&Ps[row][col] = *(const float4*)(Qh + (size_t)(i0 + row) * DK_ + col);
  }
  __syncthreads();
  float4 qreg[4][16];
#pragma unroll
  for (int i = 0; i < 4; ++i)
#pragma unroll
    for (int d4 = 0; d4 < 16; ++d4)
      qreg[i][d4] = *(float4*)&Ps[tr * 4 + i][d4 * 4];

  float m_i[4], l_i[4];
  float4 acc[4];
#pragma unroll
  for (int i = 0; i < 4; ++i) {
    m_i[i] = -1e30f; l_i[i] = 0.f;
    acc[i] = make_float4(0.f, 0.f, 0.f, 0.f);
  }

  int start, t_lo, t_hi;
  if (qt == 0) { start = 0; t_lo = 0; t_hi = 31; }
  else {
    start = -1;                           // -1 encodes "global tile 0 first"
    t_lo = qt - 4 < 1 ? 1 : qt - 4;
    t_hi = qt + 4 > 31 ? 31 : qt + 4;
  }

  for (int tt = start; tt <= t_hi; ++tt) {
    if (tt >= 0 && tt < t_lo) continue;
    const int kt = (tt < 0) ? 0 : tt;
    const int k0 = kt * 64;

    __syncthreads();   // prev PV readers done (first iter: Q-hoist done)
#pragma unroll
    for (int r = 0; r < 4; ++r) {
      const int f = tid + r * 256;
      const int row = f >> 4, col = (f & 15) * 4;
      *(float4*)&Ks[row][col] = *(const float4*)(Kh + (size_t)(k0 + row) * DK_ + col);
      *(float4*)&Vs[row][col] = *(const float4*)(Vh + (size_t)(k0 + row) * DK_ + col);
    }
    __syncthreads();

    // additive key mask for this thread's 4 keys
    float am[4];
#pragma unroll
    for (int u = 0; u < 4; ++u) am[u] = amask[b * S_ + k0 + tc + 16 * u];

    // ---- scores: 4 rows x 4 keys ----
    float s[4][4];
#pragma unroll
    for (int i = 0; i < 4; ++i)
#pragma unroll
      for (int u = 0; u < 4; ++u) s[i][u] = 0.f;
#pragma unroll
    for (int d4 = 0; d4 < 16; ++d4) {
      const float4 k0v = *(float4*)&Ks[tc     ][d4 * 4];
      const float4 k1v = *(float4*)&Ks[tc + 16][d4 * 4];
      const float4 k2v = *(float4*)&Ks[tc + 32][d4 * 4];
      const float4 k3v = *(float4*)&Ks[tc + 48][d4 * 4];
#pragma unroll
      for (int i = 0; i < 4; ++i) {
        const float4 q = qreg[i][d4];
        s[i][0] += q.x*k0v.x + q.y*k0v.y + q.z*k0v.z + q.w*k0v.w;
        s[i][1] += q.x*k1v.x + q.y*k1v.y + q.z*k1v.z + q.w*k1v.w;
        s[i][2] += q.x*k2v.x + q.y*k2v.y + q.z*k2v.z + q.w*k2v.w;
        s[i][3] += q.x*k3v.x + q.y*k3v.y + q.z*k3v.z + q.w*k3v.w;
      }
    }

    // ---- mask + scale ----
#pragma unroll
    for (int i = 0; i < 4; ++i) {
      const int irow = i0 + tr * 4 + i;
#pragma unroll
      for (int u = 0; u < 4; ++u) {
        const int j = k0 + tc + 16 * u;
        const int diff = irow - j;
        const bool allowed = (diff <= WIN_ && diff >= -WIN_) || (irow < GLB_) || (j < GLB_);
        s[i][u] = allowed ? fmaf(s[i][u], 0.125f, am[u]) : -1e30f;
      }
    }

    // ---- online softmax, wave-local shuffles over the 16 row-lanes ----
    float mt[4];
#pragma unroll
    for (int i = 0; i < 4; ++i)
      mt[i] = fmaxf(fmaxf(s[i][0], s[i][1]), fmaxf(s[i][2], s[i][3]));
#pragma unroll
    for (int st = 1; st <= 8; st <<= 1)
#pragma unroll
      for (int i = 0; i < 4; ++i)
        mt[i] = fmaxf(mt[i], __shfl_xor(mt[i], st));

    float alpha[4], rs[4];
#pragma unroll
    for (int i = 0; i < 4; ++i) {
      const float mn = fmaxf(m_i[i], mt[i]);
      alpha[i] = __expf(m_i[i] - mn);
      m_i[i] = mn;
      float r = 0.f;
#pragma unroll
      for (int u = 0; u < 4; ++u) {
        s[i][u] = __expf(s[i][u] - mn);
        r += s[i][u];
      }
      rs[i] = r;
    }
#pragma unroll
    for (int st = 1; st <= 8; st <<= 1)
#pragma unroll
      for (int i = 0; i < 4; ++i)
        rs[i] += __shfl_xor(rs[i], st);
#pragma unroll
    for (int i = 0; i < 4; ++i) {
      l_i[i] = l_i[i] * alpha[i] + rs[i];
      acc[i].x *= alpha[i]; acc[i].y *= alpha[i];
      acc[i].z *= alpha[i]; acc[i].w *= alpha[i];
    }

    // ---- write P transposed: Ps[key][row] ----
#pragma unroll
    for (int u = 0; u < 4; ++u)
      *(float4*)&Ps[tc + 16 * u][tr * 4] =
          make_float4(s[0][u], s[1][u], s[2][u], s[3][u]);
    __syncthreads();

    // ---- PV: rows tr*4..+3, dims tc*4..+3 ----
#pragma unroll 4
    for (int j = 0; j < 64; ++j) {
      const float4 p4 = *(float4*)&Ps[j][tr * 4];
      const float4 v4 = *(float4*)&Vs[j][tc * 4];
      acc[0].x = fmaf(p4.x, v4.x, acc[0].x); acc[0].y = fmaf(p4.x, v4.y, acc[0].y);
      acc[0].z = fmaf(p4.x, v4.z, acc[0].z); acc[0].w = fmaf(p4.x, v4.w, acc[0].w);
      acc[1].x = fmaf(p4.y, v4.x, acc[1].x); acc[1].y = fmaf(p4.y, v4.y, acc[1].y);
      acc[1].z = fmaf(p4.y, v4.z, acc[1].z); acc[1].w = fmaf(p4.y, v4.w, acc[1].w);
      acc[2].x = fmaf(p4.z, v4.x, acc[2].x); acc[2].y = fmaf(p4.z, v4.y, acc[2].y);
      acc[2].z = fmaf(p4.z, v4.z, acc[2].z); acc[2].w = fmaf(p4.z, v4.w, acc[2].w);
      acc[3].x = fmaf(p4.w, v4.x, acc[3].x); acc[3].y = fmaf(p4.w, v4.y, acc[3].y);
      acc[3].z = fmaf(p4.w, v4.z, acc[3].z); acc[3].w = fmaf(p4.w, v4.w, acc[3].w);
    }
  }

  // ---- epilogue ----
#pragma unroll
  for (int i = 0; i < 4; ++i) {
    const float linv = 1.0f / l_i[i];
    const int row = i0 + tr * 4 + i;
    float* dst = AO + ((size_t)b * S_ + row) * D_ + h * DK_ + tc * 4;
    *(float4*)dst = make_float4(acc[i].x * linv, acc[i].y * linv,
                                acc[i].z * linv, acc[i].w * linv);
  }
}

// ---------------------------------------------------------------------------
extern "C" void kernel_launch(void* const* d_in, const int* in_sizes, int n_in,
                              void* d_out, int out_size, void* d_ws, size_t ws_size,
                              hipStream_t stream) {
  const float* q  = (const float*)d_in[0];
  const float* k  = (const float*)d_in[1];
  const float* v  = (const float*)d_in[2];
  const float* am = (const float*)d_in[3];
  const float* wq = (const float*)d_in[4];
  const float* bq = (const float*)d_in[5];
  const float* wk = (const float*)d_in[6];
  const float* bk = (const float*)d_in[7];
  const float* wv = (const float*)d_in[8];
  const float* bv = (const float*)d_in[9];
  const float* wo = (const float*)d_in[10];
  const float* bo = (const float*)d_in[11];
  float* out = (float*)d_out;

  const size_t PER = (size_t)B_ * H_ * S_ * DK_;
  float* Qp = (float*)d_ws;
  float* Kp = Qp + PER;
  float* Vp = Kp + PER;
  float* AO = Vp + PER;

  dim3 gg(D_ / BN, (B_ * S_) / BM);
  gemm_f32<<<gg, 256, 0, stream>>>(q, wq, bq, Qp, 1);
  gemm_f32<<<gg, 256, 0, stream>>>(k, wk, bk, Kp, 1);
  gemm_f32<<<gg, 256, 0, stream>>>(v, wv, bv, Vp, 1);
  attn_v2<<<dim3(S_ / 64, H_, B_), 256, 0, stream>>>(Qp, Kp, Vp, am, AO);
  gemm_f32<<<gg, 256, 0, stream>>>(AO, wo, bo, out, 0);
}

// Round 3
// 7218.481 us; speedup vs baseline: 1.3856x; 1.3856x over previous
//
#include <hip/hip_runtime.h>

// SparseMultiHeadAttention: B=4 S=2048 D=1024 H=16 DK=64 WINDOW=256 GLOBAL=16
// Round 3:
//  - attn_v3: v2 structure minus the 256-float qreg hoist (that spilled to
//    scratch: 12.9 GB HBM traffic, VALUBusy 3%). Q now read from LDS.
//  - GEMMs: split-bf16 MFMA (x = hi + lo bf16; hi*hi + hi*lo + lo*hi),
//    m97-style: 128x128 tile, BK=32, global_load_lds(16B) staging,
//    lane-linear LDS layout, mfma_f32_16x16x32_bf16.
//  - split/transpose pre-pass kernels produce bf16 hi/lo operands.
// ws layout (138.4 MB; falls back to fp32 GEMM path if ws_size is smaller):
//  R0 [0,96MiB): Qp,Kp,Vp fp32 -> later reused for AO hi/lo
//  R1 [96MiB,+33.5MB): act hi/lo (q,k,v sequentially) -> later AO fp32
//  R2 [128MiB,+4MB): weight hi/lo (per-GEMM, sequential reuse)

#define B_   4
#define S_   2048
#define D_   1024
#define H_   16
#define DK_  64
#define WIN_ 256
#define GLB_ 16

typedef __attribute__((ext_vector_type(8))) short bf16x8;
typedef __attribute__((ext_vector_type(4))) float floatx4;

__device__ __forceinline__ unsigned short f2bf(float x) {
  unsigned u = __float_as_uint(x);
  unsigned r = u + 0x7FFFu + ((u >> 16) & 1u);   // round-to-nearest-even
  return (unsigned short)(r >> 16);
}
__device__ __forceinline__ float bf2f(unsigned short h) {
  return __uint_as_float(((unsigned)h) << 16);
}
__device__ __forceinline__ void gload_lds16(const void* g, void* l) {
  __builtin_amdgcn_global_load_lds(
      (const __attribute__((address_space(1))) unsigned int*)g,
      (__attribute__((address_space(3))) unsigned int*)l, 16, 0, 0);
}

// ---------------------------------------------------------------------------
// split: fp32 array -> bf16 hi + bf16 lo arrays. One float4 per thread.
// ---------------------------------------------------------------------------
__global__ void split_bf16(const float* __restrict__ x,
                           unsigned short* __restrict__ hi,
                           unsigned short* __restrict__ lo)
{
  const int i = blockIdx.x * 256 + threadIdx.x;
  const float4 v = ((const float4*)x)[i];
  unsigned short h0 = f2bf(v.x), h1 = f2bf(v.y), h2 = f2bf(v.z), h3 = f2bf(v.w);
  unsigned short l0 = f2bf(v.x - bf2f(h0)), l1 = f2bf(v.y - bf2f(h1));
  unsigned short l2 = f2bf(v.z - bf2f(h2)), l3 = f2bf(v.w - bf2f(h3));
  unsigned long long hp = (unsigned long long)h0 | ((unsigned long long)h1 << 16)
                        | ((unsigned long long)h2 << 32) | ((unsigned long long)h3 << 48);
  unsigned long long lp = (unsigned long long)l0 | ((unsigned long long)l1 << 16)
                        | ((unsigned long long)l2 << 32) | ((unsigned long long)l3 << 48);
  ((unsigned long long*)hi)[i] = hp;
  ((unsigned long long*)lo)[i] = lp;
}

// ---------------------------------------------------------------------------
// weight transpose+split: W[k][n] (1024x1024 fp32) -> WT_hi[n][k], WT_lo[n][k]
// ---------------------------------------------------------------------------
__global__ void wtsplit(const float* __restrict__ W,
                        unsigned short* __restrict__ hiT,
                        unsigned short* __restrict__ loT)
{
  __shared__ float t[32][33];
  const int bx = blockIdx.x * 32;   // n base
  const int by = blockIdx.y * 32;   // k base
  const int c = threadIdx.x & 31;
  const int r0 = (threadIdx.x >> 5) * 4;
#pragma unroll
  for (int i = 0; i < 4; ++i)
    t[r0 + i][c] = W[(size_t)(by + r0 + i) * 1024 + bx + c];
  __syncthreads();
#pragma unroll
  for (int i = 0; i < 4; ++i) {
    const int r = r0 + i;
    const float val = t[c][r];                     // = W[by+c][bx+r]
    const unsigned short h = f2bf(val);
    hiT[(size_t)(bx + r) * 1024 + by + c] = h;
    loT[(size_t)(bx + r) * 1024 + by + c] = f2bf(val - bf2f(h));
  }
}

// ---------------------------------------------------------------------------
// Split-bf16 MFMA GEMM: C = A(8192x1024) @ W(1024x1024) + bias
// A given as Ahi/Alo [m][k] bf16; W as WThi/WTlo [n][k] bf16 (pre-transposed).
// Block 256 thr = 4 waves (2x2 of 64x64), tile 128x128, BK=32.
// LDS tiles in lane-linear group layout: group g holds rows g*16..g*16+15,
// lane L's 16B = row (L&15), k-chunk (L>>4)  -> frag ds_read is base+L*16.
// mode 0: row-major out; mode 1: (b,h,s,dk) head layout out.
// ---------------------------------------------------------------------------
__global__ __launch_bounds__(256, 2) void gemm_mfma(
    const unsigned short* __restrict__ Ahi, const unsigned short* __restrict__ Alo,
    const unsigned short* __restrict__ WThi, const unsigned short* __restrict__ WTlo,
    const float* __restrict__ bias, float* __restrict__ C, int mode)
{
  __shared__ unsigned short AsH[4096], AsL[4096], WsH[4096], WsL[4096];
  const int tid = threadIdx.x;
  const int w = tid >> 6, lane = tid & 63;
  const int wr = w >> 1, wc = w & 1;
  const int bm = blockIdx.y * 128, bn = blockIdx.x * 128;
  const int lrow = lane & 15, lk8 = (lane >> 4) * 8;

  floatx4 acc[4][4];
#pragma unroll
  for (int t = 0; t < 4; ++t)
#pragma unroll
    for (int u = 0; u < 4; ++u) acc[t][u] = (floatx4){0.f, 0.f, 0.f, 0.f};

  // wave w stages one 8KB buffer (8 groups of 1KB)
  const unsigned short* gsrc;
  unsigned short* lbase;
  int growbase;
  if      (w == 0) { gsrc = Ahi;  lbase = AsH; growbase = bm; }
  else if (w == 1) { gsrc = Alo;  lbase = AsL; growbase = bm; }
  else if (w == 2) { gsrc = WThi; lbase = WsH; growbase = bn; }
  else             { gsrc = WTlo; lbase = WsL; growbase = bn; }

  for (int k0 = 0; k0 < 1024; k0 += 32) {
    __syncthreads();   // previous iteration's frag reads complete
#pragma unroll
    for (int g = 0; g < 8; ++g) {
      const unsigned short* gp =
          gsrc + (size_t)(growbase + g * 16 + lrow) * 1024 + k0 + lk8;
      gload_lds16(gp, lbase + g * 512);
    }
    __syncthreads();   // staging drained (barrier implies vmcnt(0))

    bf16x8 ah[4], al[4], bh[4], bl[4];
#pragma unroll
    for (int t = 0; t < 4; ++t) {
      ah[t] = *(const bf16x8*)&AsH[(wr * 4 + t) * 512 + lane * 8];
      al[t] = *(const bf16x8*)&AsL[(wr * 4 + t) * 512 + lane * 8];
    }
#pragma unroll
    for (int u = 0; u < 4; ++u) {
      bh[u] = *(const bf16x8*)&WsH[(wc * 4 + u) * 512 + lane * 8];
      bl[u] = *(const bf16x8*)&WsL[(wc * 4 + u) * 512 + lane * 8];
    }
#pragma unroll
    for (int t = 0; t < 4; ++t)
#pragma unroll
      for (int u = 0; u < 4; ++u) {
        acc[t][u] = __builtin_amdgcn_mfma_f32_16x16x32_bf16(ah[t], bh[u], acc[t][u], 0, 0, 0);
        acc[t][u] = __builtin_amdgcn_mfma_f32_16x16x32_bf16(ah[t], bl[u], acc[t][u], 0, 0, 0);
        acc[t][u] = __builtin_amdgcn_mfma_f32_16x16x32_bf16(al[t], bh[u], acc[t][u], 0, 0, 0);
      }
  }

  float bs[4];
#pragma unroll
  for (int u = 0; u < 4; ++u) bs[u] = bias[bn + wc * 64 + u * 16 + lrow];

  if (mode == 0) {
#pragma unroll
    for (int t = 0; t < 4; ++t)
#pragma unroll
      for (int r = 0; r < 4; ++r) {
        const int row = bm + wr * 64 + t * 16 + (lane >> 4) * 4 + r;
#pragma unroll
        for (int u = 0; u < 4; ++u)
          C[(size_t)row * 1024 + bn + wc * 64 + u * 16 + lrow] = acc[t][u][r] + bs[u];
      }
  } else {
#pragma unroll
    for (int t = 0; t < 4; ++t)
#pragma unroll
      for (int r = 0; r < 4; ++r) {
        const int row = bm + wr * 64 + t * 16 + (lane >> 4) * 4 + r;
        const int bb = row >> 11, s = row & 2047;
#pragma unroll
        for (int u = 0; u < 4; ++u) {
          const int cb = bn + wc * 64 + u * 16;        // 16-col tile never crosses head
          const int h = cb >> 6, dk = (cb & 63) + lrow;
          C[((size_t)(bb * H_ + h) * S_ + s) * DK_ + dk] = acc[t][u][r] + bs[u];
        }
      }
  }
}

// ---------------------------------------------------------------------------
// fp32 fallback GEMM (round-1 kernel), used only if ws_size is too small.
// ---------------------------------------------------------------------------
#define BM 128
#define BN 128
#define BK 16

__global__ __launch_bounds__(256, 2) void gemm_f32(
    const float* __restrict__ A, const float* __restrict__ W,
    const float* __restrict__ bias, float* __restrict__ C, int mode)
{
  __shared__ float As[BK][BM + 4];
  __shared__ float Bs[BK][BN + 4];
  const int tid = threadIdx.x;
  const int bm = blockIdx.y * BM;
  const int bn = blockIdx.x * BN;
  const int tx = tid & 15;
  const int ty = tid >> 4;
  const int K = 1024, N = 1024;

  float acc[8][8];
#pragma unroll
  for (int i = 0; i < 8; ++i)
#pragma unroll
    for (int j = 0; j < 8; ++j) acc[i][j] = 0.f;

  const int arow = tid >> 2;
  const int acol = (tid & 3) * 4;
  const int brow = tid >> 5;
  const int bcol = (tid & 31) * 4;

  for (int k0 = 0; k0 < K; k0 += BK) {
    float4 a0 = *(const float4*)(A + (size_t)(bm + arow) * K + k0 + acol);
    float4 a1 = *(const float4*)(A + (size_t)(bm + arow + 64) * K + k0 + acol);
    float4 b0 = *(const float4*)(W + (size_t)(k0 + brow) * N + bn + bcol);
    float4 b1 = *(const float4*)(W + (size_t)(k0 + brow + 8) * N + bn + bcol);
    __syncthreads();
    As[acol + 0][arow] = a0.x; As[acol + 1][arow] = a0.y;
    As[acol + 2][arow] = a0.z; As[acol + 3][arow] = a0.w;
    As[acol + 0][arow + 64] = a1.x; As[acol + 1][arow + 64] = a1.y;
    As[acol + 2][arow + 64] = a1.z; As[acol + 3][arow + 64] = a1.w;
    *(float4*)&Bs[brow][bcol]     = b0;
    *(float4*)&Bs[brow + 8][bcol] = b1;
    __syncthreads();
#pragma unroll
    for (int kk = 0; kk < BK; ++kk) {
      float a[8], b[8];
      float4 t;
      t = *(float4*)&As[kk][ty * 8];     a[0]=t.x; a[1]=t.y; a[2]=t.z; a[3]=t.w;
      t = *(float4*)&As[kk][ty * 8 + 4]; a[4]=t.x; a[5]=t.y; a[6]=t.z; a[7]=t.w;
      t = *(float4*)&Bs[kk][tx * 8];     b[0]=t.x; b[1]=t.y; b[2]=t.z; b[3]=t.w;
      t = *(float4*)&Bs[kk][tx * 8 + 4]; b[4]=t.x; b[5]=t.y; b[6]=t.z; b[7]=t.w;
#pragma unroll
      for (int i = 0; i < 8; ++i)
#pragma unroll
        for (int j = 0; j < 8; ++j)
          acc[i][j] = fmaf(a[i], b[j], acc[i][j]);
    }
  }

  const float4 bias0 = *(const float4*)(bias + bn + tx * 8);
  const float4 bias1 = *(const float4*)(bias + bn + tx * 8 + 4);
  if (mode == 0) {
#pragma unroll
    for (int i = 0; i < 8; ++i) {
      const int m = bm + ty * 8 + i;
      float* dst = C + (size_t)m * 1024 + bn + tx * 8;
      *(float4*)dst = make_float4(acc[i][0] + bias0.x, acc[i][1] + bias0.y,
                                  acc[i][2] + bias0.z, acc[i][3] + bias0.w);
      *(float4*)(dst + 4) = make_float4(acc[i][4] + bias1.x, acc[i][5] + bias1.y,
                                        acc[i][6] + bias1.z, acc[i][7] + bias1.w);
    }
  } else {
    const int ncol = bn + tx * 8;
    const int h  = ncol >> 6;
    const int dk = ncol & 63;
#pragma unroll
    for (int i = 0; i < 8; ++i) {
      const int m = bm + ty * 8 + i;
      const int bb = m >> 11;
      const int s  = m & 2047;
      float* dst = C + ((size_t)(bb * H_ + h) * S_ + s) * DK_ + dk;
      *(float4*)dst = make_float4(acc[i][0] + bias0.x, acc[i][1] + bias0.y,
                                  acc[i][2] + bias0.z, acc[i][3] + bias0.w);
      *(float4*)(dst + 4) = make_float4(acc[i][4] + bias1.x, acc[i][5] + bias1.y,
                                        acc[i][6] + bias1.z, acc[i][7] + bias1.w);
    }
  }
}

// ---------------------------------------------------------------------------
// Banded attention v3: v2 structure, Q kept in LDS (no register hoist/spill).
// Block = 256 threads; 64-row Q tile x 64-key K tiles; 4x4 per-thread tile;
// wave-shuffle softmax; P via transposed LDS.
// ---------------------------------------------------------------------------
__global__ __launch_bounds__(256, 2) void attn_v3(
    const float* __restrict__ Qp, const float* __restrict__ Kp,
    const float* __restrict__ Vp, const float* __restrict__ amask,
    float* __restrict__ AO)
{
  __shared__ float Qs[64][68], Ks[64][68], Vs[64][68], Ps[64][68];  // 69,632 B

  const int tid = threadIdx.x;
  const int qt = blockIdx.x;   // 0..31
  const int h  = blockIdx.y;
  const int b  = blockIdx.z;
  const int i0 = qt * 64;
  const int tr = tid >> 4;     // 0..15 -> rows tr*4..tr*4+3
  const int tc = tid & 15;

  const size_t head_off = (size_t)(b * H_ + h) * S_ * DK_;
  const float* Qh = Qp + head_off;
  const float* Kh = Kp + head_off;
  const float* Vh = Vp + head_off;

  // stage Q tile (64x64)
#pragma unroll
  for (int r = 0; r < 4; ++r) {
    const int f = tid + r * 256;
    const int row = f >> 4, col = (f & 15) * 4;
    *(float4*)&Qs[row][col] = *(const float4*)(Qh + (size_t)(i0 + row) * DK_ + col);
  }

  float m_i[4], l_i[4];
  float4 acc[4];
#pragma unroll
  for (int i = 0; i < 4; ++i) {
    m_i[i] = -1e30f; l_i[i] = 0.f;
    acc[i] = make_float4(0.f, 0.f, 0.f, 0.f);
  }

  int start, t_lo, t_hi;
  if (qt == 0) { start = 0; t_lo = 0; t_hi = 31; }
  else {
    start = -1;                 // -1 encodes "global tile 0 first"
    t_lo = qt - 4 < 1 ? 1 : qt - 4;
    t_hi = qt + 4 > 31 ? 31 : qt + 4;
  }

  for (int tt = start; tt <= t_hi; ++tt) {
    if (tt >= 0 && tt < t_lo) continue;
    const int kt = (tt < 0) ? 0 : tt;
    const int k0 = kt * 64;

    __syncthreads();   // prev PV readers done (first iter: Q staging ordering)
#pragma unroll
    for (int r = 0; r < 4; ++r) {
      const int f = tid + r * 256;
      const int row = f >> 4, col = (f & 15) * 4;
      *(float4*)&Ks[row][col] = *(const float4*)(Kh + (size_t)(k0 + row) * DK_ + col);
      *(float4*)&Vs[row][col] = *(const float4*)(Vh + (size_t)(k0 + row) * DK_ + col);
    }
    __syncthreads();

    float am[4];
#pragma unroll
    for (int u = 0; u < 4; ++u) am[u] = amask[b * S_ + k0 + tc + 16 * u];

    // ---- scores: 4 rows x 4 keys, Q and K from LDS ----
    float s[4][4];
#pragma unroll
    for (int i = 0; i < 4; ++i)
#pragma unroll
      for (int u = 0; u < 4; ++u) s[i][u] = 0.f;
#pragma unroll
    for (int d4 = 0; d4 < 16; ++d4) {
      const float4 k0v = *(float4*)&Ks[tc     ][d4 * 4];
      const float4 k1v = *(float4*)&Ks[tc + 16][d4 * 4];
      const float4 k2v = *(float4*)&Ks[tc + 32][d4 * 4];
      const float4 k3v = *(float4*)&Ks[tc + 48][d4 * 4];
#pragma unroll
      for (int i = 0; i < 4; ++i) {
        const float4 q = *(float4*)&Qs[tr * 4 + i][d4 * 4];
        s[i][0] += q.x*k0v.x + q.y*k0v.y + q.z*k0v.z + q.w*k0v.w;
        s[i][1] += q.x*k1v.x + q.y*k1v.y + q.z*k1v.z + q.w*k1v.w;
        s[i][2] += q.x*k2v.x + q.y*k2v.y + q.z*k2v.z + q.w*k2v.w;
        s[i][3] += q.x*k3v.x + q.y*k3v.y + q.z*k3v.z + q.w*k3v.w;
      }
    }

    // ---- mask + scale ----
#pragma unroll
    for (int i = 0; i < 4; ++i) {
      const int irow = i0 + tr * 4 + i;
#pragma unroll
      for (int u = 0; u < 4; ++u) {
        const int j = k0 + tc + 16 * u;
        const int diff = irow - j;
        const bool allowed = (diff <= WIN_ && diff >= -WIN_) || (irow < GLB_) || (j < GLB_);
        s[i][u] = allowed ? fmaf(s[i][u], 0.125f, am[u]) : -1e30f;
      }
    }

    // ---- online softmax via wave shuffles over the 16 row-lanes ----
    float mt[4];
#pragma unroll
    for (int i = 0; i < 4; ++i)
      mt[i] = fmaxf(fmaxf(s[i][0], s[i][1]), fmaxf(s[i][2], s[i][3]));
#pragma unroll
    for (int st = 1; st <= 8; st <<= 1)
#pragma unroll
      for (int i = 0; i < 4; ++i)
        mt[i] = fmaxf(mt[i], __shfl_xor(mt[i], st));

    float alpha[4], rs[4];
#pragma unroll
    for (int i = 0; i < 4; ++i) {
      const float mn = fmaxf(m_i[i], mt[i]);
      alpha[i] = __expf(m_i[i] - mn);
      m_i[i] = mn;
      float r = 0.f;
#pragma unroll
      for (int u = 0; u < 4; ++u) {
        s[i][u] = __expf(s[i][u] - mn);
        r += s[i][u];
      }
      rs[i] = r;
    }
#pragma unroll
    for (int st = 1; st <= 8; st <<= 1)
#pragma unroll
      for (int i = 0; i < 4; ++i)
        rs[i] += __shfl_xor(rs[i], st);
#pragma unroll
    for (int i = 0; i < 4; ++i) {
      l_i[i] = l_i[i] * alpha[i] + rs[i];
      acc[i].x *= alpha[i]; acc[i].y *= alpha[i];
      acc[i].z *= alpha[i]; acc[i].w *= alpha[i];
    }

    // ---- write P transposed: Ps[key][row] ----
#pragma unroll
    for (int u = 0; u < 4; ++u)
      *(float4*)&Ps[tc + 16 * u][tr * 4] =
          make_float4(s[0][u], s[1][u], s[2][u], s[3][u]);
    __syncthreads();

    // ---- PV: rows tr*4..+3, dims tc*4..+3 ----
#pragma unroll 4
    for (int j = 0; j < 64; ++j) {
      const float4 p4 = *(float4*)&Ps[j][tr * 4];
      const float4 v4 = *(float4*)&Vs[j][tc * 4];
      acc[0].x = fmaf(p4.x, v4.x, acc[0].x); acc[0].y = fmaf(p4.x, v4.y, acc[0].y);
      acc[0].z = fmaf(p4.x, v4.z, acc[0].z); acc[0].w = fmaf(p4.x, v4.w, acc[0].w);
      acc[1].x = fmaf(p4.y, v4.x, acc[1].x); acc[1].y = fmaf(p4.y, v4.y, acc[1].y);
      acc[1].z = fmaf(p4.y, v4.z, acc[1].z); acc[1].w = fmaf(p4.y, v4.w, acc[1].w);
      acc[2].x = fmaf(p4.z, v4.x, acc[2].x); acc[2].y = fmaf(p4.z, v4.y, acc[2].y);
      acc[2].z = fmaf(p4.z, v4.z, acc[2].z); acc[2].w = fmaf(p4.z, v4.w, acc[2].w);
      acc[3].x = fmaf(p4.w, v4.x, acc[3].x); acc[3].y = fmaf(p4.w, v4.y, acc[3].y);
      acc[3].z = fmaf(p4.w, v4.z, acc[3].z); acc[3].w = fmaf(p4.w, v4.w, acc[3].w);
    }
  }

  // ---- epilogue ----
#pragma unroll
  for (int i = 0; i < 4; ++i) {
    const float linv = 1.0f / l_i[i];
    const int row = i0 + tr * 4 + i;
    float* dst = AO + ((size_t)b * S_ + row) * D_ + h * DK_ + tc * 4;
    *(float4*)dst = make_float4(acc[i].x * linv, acc[i].y * linv,
                                acc[i].z * linv, acc[i].w * linv);
  }
}

// ---------------------------------------------------------------------------
extern "C" void kernel_launch(void* const* d_in, const int* in_sizes, int n_in,
                              void* d_out, int out_size, void* d_ws, size_t ws_size,
                              hipStream_t stream) {
  const float* q  = (const float*)d_in[0];
  const float* k  = (const float*)d_in[1];
  const float* v  = (const float*)d_in[2];
  const float* am = (const float*)d_in[3];
  const float* wq = (const float*)d_in[4];
  const float* bq = (const float*)d_in[5];
  const float* wk = (const float*)d_in[6];
  const float* bk = (const float*)d_in[7];
  const float* wv = (const float*)d_in[8];
  const float* bv = (const float*)d_in[9];
  const float* wo = (const float*)d_in[10];
  const float* bo = (const float*)d_in[11];
  float* out = (float*)d_out;

  const size_t PER = (size_t)B_ * H_ * S_ * DK_;   // 8,388,608 elements
  char* base = (char*)d_ws;
  float* Qp = (float*)base;
  float* Kp = Qp + PER;
  float* Vp = Kp + PER;
  float* AOf = Vp + PER;                            // R1 as fp32 (attn output)

  const size_t NEED = 138412032;                    // 132 MiB
  if (ws_size >= NEED) {
    unsigned short* AHI = (unsigned short*)AOf;     // R1 as act hi/lo
    unsigned short* ALO = AHI + PER;
    unsigned short* OHI = (unsigned short*)base;    // R0 reuse for AO hi/lo
    unsigned short* OLO = OHI + PER;
    unsigned short* WHI = (unsigned short*)(base + 134217728);
    unsigned short* WLO = WHI + 1048576;

    const int sgrid = (int)(PER / 4 / 256);         // 8192 blocks
    dim3 wgrid(32, 32);
    dim3 ggrid(8, 64);

    split_bf16<<<sgrid, 256, 0, stream>>>(q, AHI, ALO);
    wtsplit<<<wgrid, 256, 0, stream>>>(wq, WHI, WLO);
    gemm_mfma<<<ggrid, 256, 0, stream>>>(AHI, ALO, WHI, WLO, bq, Qp, 1);

    split_bf16<<<sgrid, 256, 0, stream>>>(k, AHI, ALO);
    wtsplit<<<wgrid, 256, 0, stream>>>(wk, WHI, WLO);
    gemm_mfma<<<ggrid, 256, 0, stream>>>(AHI, ALO, WHI, WLO, bk, Kp, 1);

    split_bf16<<<sgrid, 256, 0, stream>>>(v, AHI, ALO);
    wtsplit<<<wgrid, 256, 0, stream>>>(wv, WHI, WLO);
    gemm_mfma<<<ggrid, 256, 0, stream>>>(AHI, ALO, WHI, WLO, bv, Vp, 1);

    attn_v3<<<dim3(S_ / 64, H_, B_), 256, 0, stream>>>(Qp, Kp, Vp, am, AOf);

    split_bf16<<<sgrid, 256, 0, stream>>>(AOf, OHI, OLO);
    wtsplit<<<wgrid, 256, 0, stream>>>(wo, WHI, WLO);
    gemm_mfma<<<ggrid, 256, 0, stream>>>(OHI, OLO, WHI, WLO, bo, out, 0);
  } else {
    dim3 gg(D_ / BN, (B_ * S_) / BM);
    gemm_f32<<<gg, 256, 0, stream>>>(q, wq, bq, Qp, 1);
    gemm_f32<<<gg, 256, 0, stream>>>(k, wk, bk, Kp, 1);
    gemm_f32<<<gg, 256, 0, stream>>>(v, wv, bv, Vp, 1);
    attn_v3<<<dim3(S_ / 64, H_, B_), 256, 0, stream>>>(Qp, Kp, Vp, am, AOf);
    gemm_f32<<<gg, 256, 0, stream>>>(AOf, wo, bo, out, 0);
  }
}

// Round 4
// 749.682 us; speedup vs baseline: 13.3420x; 9.6287x over previous
//
#include <hip/hip_runtime.h>

// SparseMultiHeadAttention: B=4 S=2048 D=1024 H=16 DK=64 WINDOW=256 GLOBAL=16
// Round 4: MFMA flash attention (the fp32 vector attn kept scratch-thrashing:
// 11.2 GB HBM traffic, VALUBusy 4.5%). All heavy math now 16x16x32 bf16 MFMA.
//   - proj GEMMs emit Q,K split-bf16 (head layout) and V bf16 transposed
//     [b][h][dk][s] straight from the epilogue.
//   - attn: 64-row Q tile, 4 waves; per 64-key tile stage Khi/Klo/Vt via
//     global_load_lds(16B) frag-linear; QK^T 3-product split; shfl softmax;
//     P->LDS chunk-major; PV bf16; AO written split-bf16 for out-proj.
// ws (121.7 MB used; guard 138412032 from round 3, else fp32 fallback).

#define B_   4
#define S_   2048
#define D_   1024
#define H_   16
#define DK_  64
#define WIN_ 256
#define GLB_ 16

typedef __attribute__((ext_vector_type(8))) short bf16x8;
typedef __attribute__((ext_vector_type(4))) float floatx4;

__device__ __forceinline__ unsigned short f2bf(float x) {
  unsigned u = __float_as_uint(x);
  unsigned r = u + 0x7FFFu + ((u >> 16) & 1u);
  return (unsigned short)(r >> 16);
}
__device__ __forceinline__ float bf2f(unsigned short h) {
  return __uint_as_float(((unsigned)h) << 16);
}
__device__ __forceinline__ void gload_lds16(const void* g, void* l) {
  __builtin_amdgcn_global_load_lds(
      (const __attribute__((address_space(1))) unsigned int*)g,
      (__attribute__((address_space(3))) unsigned int*)l, 16, 0, 0);
}

// ---------------------------------------------------------------------------
__global__ void split_bf16(const float* __restrict__ x,
                           unsigned short* __restrict__ hi,
                           unsigned short* __restrict__ lo)
{
  const int i = blockIdx.x * 256 + threadIdx.x;
  const float4 v = ((const float4*)x)[i];
  unsigned short h0 = f2bf(v.x), h1 = f2bf(v.y), h2 = f2bf(v.z), h3 = f2bf(v.w);
  unsigned short l0 = f2bf(v.x - bf2f(h0)), l1 = f2bf(v.y - bf2f(h1));
  unsigned short l2 = f2bf(v.z - bf2f(h2)), l3 = f2bf(v.w - bf2f(h3));
  unsigned long long hp = (unsigned long long)h0 | ((unsigned long long)h1 << 16)
                        | ((unsigned long long)h2 << 32) | ((unsigned long long)h3 << 48);
  unsigned long long lp = (unsigned long long)l0 | ((unsigned long long)l1 << 16)
                        | ((unsigned long long)l2 << 32) | ((unsigned long long)l3 << 48);
  ((unsigned long long*)hi)[i] = hp;
  ((unsigned long long*)lo)[i] = lp;
}

// ---------------------------------------------------------------------------
__global__ void wtsplit(const float* __restrict__ W,
                        unsigned short* __restrict__ hiT,
                        unsigned short* __restrict__ loT)
{
  __shared__ float t[32][33];
  const int bx = blockIdx.x * 32;   // n base
  const int by = blockIdx.y * 32;   // k base
  const int c = threadIdx.x & 31;
  const int r0 = (threadIdx.x >> 5) * 4;
#pragma unroll
  for (int i = 0; i < 4; ++i)
    t[r0 + i][c] = W[(size_t)(by + r0 + i) * 1024 + bx + c];
  __syncthreads();
#pragma unroll
  for (int i = 0; i < 4; ++i) {
    const int r = r0 + i;
    const float val = t[c][r];
    const unsigned short h = f2bf(val);
    hiT[(size_t)(bx + r) * 1024 + by + c] = h;
    loT[(size_t)(bx + r) * 1024 + by + c] = f2bf(val - bf2f(h));
  }
}

// ---------------------------------------------------------------------------
// Split-bf16 MFMA GEMM (verified round 3). Epilogue modes:
//  0: fp32 row-major (out-proj)
//  1: split-bf16 head layout (b,h,s,dk)  -> Chi/Clo   (Q, K)
//  2: bf16 transposed head layout (b,h,dk,s) -> Chi   (V)
// ---------------------------------------------------------------------------
__global__ __launch_bounds__(256, 2) void gemm_mfma(
    const unsigned short* __restrict__ Ahi, const unsigned short* __restrict__ Alo,
    const unsigned short* __restrict__ WThi, const unsigned short* __restrict__ WTlo,
    const float* __restrict__ bias, float* __restrict__ Cf,
    unsigned short* __restrict__ Chi, unsigned short* __restrict__ Clo, int mode)
{
  __shared__ unsigned short AsH[4096], AsL[4096], WsH[4096], WsL[4096];
  const int tid = threadIdx.x;
  const int w = tid >> 6, lane = tid & 63;
  const int wr = w >> 1, wc = w & 1;
  const int bm = blockIdx.y * 128, bn = blockIdx.x * 128;
  const int lrow = lane & 15, lk8 = (lane >> 4) * 8;

  floatx4 acc[4][4];
#pragma unroll
  for (int t = 0; t < 4; ++t)
#pragma unroll
    for (int u = 0; u < 4; ++u) acc[t][u] = (floatx4){0.f, 0.f, 0.f, 0.f};

  const unsigned short* gsrc;
  unsigned short* lbase;
  int growbase;
  if      (w == 0) { gsrc = Ahi;  lbase = AsH; growbase = bm; }
  else if (w == 1) { gsrc = Alo;  lbase = AsL; growbase = bm; }
  else if (w == 2) { gsrc = WThi; lbase = WsH; growbase = bn; }
  else             { gsrc = WTlo; lbase = WsL; growbase = bn; }

  for (int k0 = 0; k0 < 1024; k0 += 32) {
    __syncthreads();
#pragma unroll
    for (int g = 0; g < 8; ++g) {
      const unsigned short* gp =
          gsrc + (size_t)(growbase + g * 16 + lrow) * 1024 + k0 + lk8;
      gload_lds16(gp, lbase + g * 512);
    }
    __syncthreads();

    bf16x8 ah[4], al[4], bh[4], bl[4];
#pragma unroll
    for (int t = 0; t < 4; ++t) {
      ah[t] = *(const bf16x8*)&AsH[(wr * 4 + t) * 512 + lane * 8];
      al[t] = *(const bf16x8*)&AsL[(wr * 4 + t) * 512 + lane * 8];
    }
#pragma unroll
    for (int u = 0; u < 4; ++u) {
      bh[u] = *(const bf16x8*)&WsH[(wc * 4 + u) * 512 + lane * 8];
      bl[u] = *(const bf16x8*)&WsL[(wc * 4 + u) * 512 + lane * 8];
    }
#pragma unroll
    for (int t = 0; t < 4; ++t)
#pragma unroll
      for (int u = 0; u < 4; ++u) {
        acc[t][u] = __builtin_amdgcn_mfma_f32_16x16x32_bf16(al[t], bh[u], acc[t][u], 0, 0, 0);
        acc[t][u] = __builtin_amdgcn_mfma_f32_16x16x32_bf16(ah[t], bl[u], acc[t][u], 0, 0, 0);
        acc[t][u] = __builtin_amdgcn_mfma_f32_16x16x32_bf16(ah[t], bh[u], acc[t][u], 0, 0, 0);
      }
  }

  float bs[4];
#pragma unroll
  for (int u = 0; u < 4; ++u) bs[u] = bias[bn + wc * 64 + u * 16 + lrow];

#pragma unroll
  for (int t = 0; t < 4; ++t)
#pragma unroll
    for (int r = 0; r < 4; ++r) {
      const int row = bm + wr * 64 + t * 16 + (lane >> 4) * 4 + r;
#pragma unroll
      for (int u = 0; u < 4; ++u) {
        const int col = bn + wc * 64 + u * 16 + lrow;
        const float val = acc[t][u][r] + bs[u];
        if (mode == 0) {
          Cf[(size_t)row * 1024 + col] = val;
        } else {
          const int bb = row >> 11, s = row & 2047;
          const int hh = col >> 6, dk = col & 63;
          if (mode == 1) {
            const size_t a = ((size_t)(bb * H_ + hh) * S_ + s) * DK_ + dk;
            const unsigned short hv = f2bf(val);
            Chi[a] = hv;
            Clo[a] = f2bf(val - bf2f(hv));
          } else {
            Chi[((size_t)(bb * H_ + hh) * DK_ + dk) * S_ + s] = f2bf(val);
          }
        }
      }
    }
}

// ---------------------------------------------------------------------------
// MFMA flash attention.
// Block 256 thr = 4 waves; block = (b, h, 64-row Q tile); wave = 16-row strip.
// LDS (shorts): Khi[0,4096) Klo[4096,8192) Vt[8192,12288) P[12288+w*1024,...)
//   K/Vt tiles frag-linear: op + group(g of 16 idx)*1024 + half*512 + lane*8.
//   P per-wave chunk-major: chunk(8 keys)*128 + row*8 + key%8.
// ---------------------------------------------------------------------------
__global__ __launch_bounds__(256, 4) void attn_mfma(
    const unsigned short* __restrict__ Qhi, const unsigned short* __restrict__ Qlo,
    const unsigned short* __restrict__ Khi, const unsigned short* __restrict__ Klo,
    const unsigned short* __restrict__ Vt,  const float* __restrict__ amask,
    unsigned short* __restrict__ AOhi, unsigned short* __restrict__ AOlo)
{
  __shared__ unsigned short lds[16384];   // 32 KB

  const int tid = threadIdx.x;
  const int w = tid >> 6, lane = tid & 63;
  const int quad = lane >> 4, lm = lane & 15;
  const int qt = blockIdx.x, h = blockIdx.y, b = blockIdx.z;
  const int i0 = qt * 64;

  const size_t hb = (size_t)(b * H_ + h) * S_ * DK_;
  const unsigned short* Qhih = Qhi + hb;
  const unsigned short* Qloh = Qlo + hb;
  const unsigned short* Khih = Khi + hb;
  const unsigned short* Kloh = Klo + hb;
  const unsigned short* Vth  = Vt  + hb;   // [dk][s] within head

  // Q a-frags: A[m=lm][k=p*32+quad*8+j], rows i0+w*16+lm
  bf16x8 aqh[2], aql[2];
#pragma unroll
  for (int p = 0; p < 2; ++p) {
    const size_t qa = (size_t)(i0 + w * 16 + lm) * DK_ + p * 32 + quad * 8;
    aqh[p] = *(const bf16x8*)(Qhih + qa);
    aql[p] = *(const bf16x8*)(Qloh + qa);
  }

  floatx4 acc_o[4];
  float m_i[4], l_i[4];
#pragma unroll
  for (int u = 0; u < 4; ++u) acc_o[u] = (floatx4){0.f, 0.f, 0.f, 0.f};
#pragma unroll
  for (int r = 0; r < 4; ++r) { m_i[r] = -1e30f; l_i[r] = 0.f; }

  int start, t_lo, t_hi;
  if (qt == 0) { start = 0; t_lo = 0; t_hi = 31; }
  else {
    start = -1;
    t_lo = qt - 4 < 1 ? 1 : qt - 4;
    t_hi = qt + 4 > 31 ? 31 : qt + 4;
  }

  unsigned short* Pb = &lds[12288 + w * 1024];

  for (int tt = start; tt <= t_hi; ++tt) {
    if (tt >= 0 && tt < t_lo) continue;
    const int kt = (tt < 0) ? 0 : tt;
    const int k0 = kt * 64;

    __syncthreads();   // prior tile's LDS reads complete
    for (int e = w; e < 24; e += 4) {
      const int op = e >> 3, cc = e & 7, g = cc >> 1, hf = cc & 1;
      unsigned short* ldst = &lds[op * 4096 + g * 1024 + hf * 512];
      const unsigned short* gp;
      if (op == 0)      gp = Khih + (size_t)(k0 + g * 16 + lm) * DK_ + (hf * 4 + quad) * 8;
      else if (op == 1) gp = Kloh + (size_t)(k0 + g * 16 + lm) * DK_ + (hf * 4 + quad) * 8;
      else              gp = Vth + (size_t)(g * 16 + lm) * S_ + k0 + (hf * 4 + quad) * 8;
      gload_lds16(gp, ldst);
    }
    __syncthreads();   // staging drained

    // ---- QK^T: split-bf16, 3 products; sc[u] covers keys u*16..u*16+15 ----
    floatx4 sc[4];
#pragma unroll
    for (int u = 0; u < 4; ++u) sc[u] = (floatx4){0.f, 0.f, 0.f, 0.f};
#pragma unroll
    for (int u = 0; u < 4; ++u)
#pragma unroll
      for (int p = 0; p < 2; ++p) {
        const bf16x8 kh = *(const bf16x8*)&lds[       u * 1024 + p * 512 + lane * 8];
        const bf16x8 kl = *(const bf16x8*)&lds[4096 + u * 1024 + p * 512 + lane * 8];
        sc[u] = __builtin_amdgcn_mfma_f32_16x16x32_bf16(aql[p], kh, sc[u], 0, 0, 0);
        sc[u] = __builtin_amdgcn_mfma_f32_16x16x32_bf16(aqh[p], kl, sc[u], 0, 0, 0);
        sc[u] = __builtin_amdgcn_mfma_f32_16x16x32_bf16(aqh[p], kh, sc[u], 0, 0, 0);
      }

    // ---- mask + scale + online softmax (per C-row r; cols across 16 lanes) --
    float am4[4];
#pragma unroll
    for (int u = 0; u < 4; ++u) am4[u] = amask[b * S_ + k0 + u * 16 + lm];

    const int ibase = i0 + w * 16 + quad * 4;
#pragma unroll
    for (int r = 0; r < 4; ++r) {
      const int i = ibase + r;
      float mx = -1e30f;
#pragma unroll
      for (int u = 0; u < 4; ++u) {
        const int j = k0 + u * 16 + lm;
        const int diff = i - j;
        const bool ok = (diff <= WIN_ && diff >= -WIN_) || (i < GLB_) || (j < GLB_);
        const float sv = ok ? fmaf(sc[u][r], 0.125f, am4[u]) : -1e30f;
        sc[u][r] = sv;
        mx = fmaxf(mx, sv);
      }
#pragma unroll
      for (int st = 1; st <= 8; st <<= 1) mx = fmaxf(mx, __shfl_xor(mx, st));
      const float mn = fmaxf(m_i[r], mx);
      const float alpha = __expf(m_i[r] - mn);
      m_i[r] = mn;
      float rsum = 0.f;
#pragma unroll
      for (int u = 0; u < 4; ++u) {
        const float pv = __expf(sc[u][r] - mn);
        sc[u][r] = pv;
        rsum += pv;
      }
#pragma unroll
      for (int st = 1; st <= 8; st <<= 1) rsum += __shfl_xor(rsum, st);
      l_i[r] = l_i[r] * alpha + rsum;
#pragma unroll
      for (int u = 0; u < 4; ++u) acc_o[u][r] *= alpha;
    }

    // ---- P -> LDS (wave-private, chunk-major) ----
#pragma unroll
    for (int u = 0; u < 4; ++u) {
      const int key = u * 16 + lm;
      const int cbase = (key >> 3) * 128 + (key & 7);
#pragma unroll
      for (int r = 0; r < 4; ++r)
        Pb[cbase + (quad * 4 + r) * 8] = f2bf(sc[u][r]);
    }

    // ---- PV: out[m][dk] += P[m][key] * Vt[dk][key] ----
#pragma unroll
    for (int p = 0; p < 2; ++p) {
      const bf16x8 pf = *(const bf16x8*)&Pb[p * 512 + lane * 8];
#pragma unroll
      for (int u = 0; u < 4; ++u) {
        const bf16x8 vf = *(const bf16x8*)&lds[8192 + u * 1024 + p * 512 + lane * 8];
        acc_o[u] = __builtin_amdgcn_mfma_f32_16x16x32_bf16(pf, vf, acc_o[u], 0, 0, 0);
      }
    }
  }

  // ---- epilogue: /l, split-bf16 AO (row-major [B*S][D]) ----
#pragma unroll
  for (int r = 0; r < 4; ++r) {
    const float linv = 1.0f / l_i[r];
    const size_t rowa = (size_t)(b * S_ + i0 + w * 16 + quad * 4 + r) * D_;
#pragma unroll
    for (int u = 0; u < 4; ++u) {
      const float val = acc_o[u][r] * linv;
      const size_t a = rowa + h * DK_ + u * 16 + lm;
      const unsigned short hv = f2bf(val);
      AOhi[a] = hv;
      AOlo[a] = f2bf(val - bf2f(hv));
    }
  }
}

// ---------------------------------------------------------------------------
// fp32 fallback (rounds 1-3), used only if ws_size < guard.
// ---------------------------------------------------------------------------
#define BM 128
#define BN 128
#define BK 16

__global__ __launch_bounds__(256, 2) void gemm_f32(
    const float* __restrict__ A, const float* __restrict__ W,
    const float* __restrict__ bias, float* __restrict__ C, int mode)
{
  __shared__ float As[BK][BM + 4];
  __shared__ float Bs[BK][BN + 4];
  const int tid = threadIdx.x;
  const int bm = blockIdx.y * BM;
  const int bn = blockIdx.x * BN;
  const int tx = tid & 15;
  const int ty = tid >> 4;
  const int K = 1024, N = 1024;

  float acc[8][8];
#pragma unroll
  for (int i = 0; i < 8; ++i)
#pragma unroll
    for (int j = 0; j < 8; ++j) acc[i][j] = 0.f;

  const int arow = tid >> 2;
  const int acol = (tid & 3) * 4;
  const int brow = tid >> 5;
  const int bcol = (tid & 31) * 4;

  for (int k0 = 0; k0 < K; k0 += BK) {
    float4 a0 = *(const float4*)(A + (size_t)(bm + arow) * K + k0 + acol);
    float4 a1 = *(const float4*)(A + (size_t)(bm + arow + 64) * K + k0 + acol);
    float4 b0 = *(const float4*)(W + (size_t)(k0 + brow) * N + bn + bcol);
    float4 b1 = *(const float4*)(W + (size_t)(k0 + brow + 8) * N + bn + bcol);
    __syncthreads();
    As[acol + 0][arow] = a0.x; As[acol + 1][arow] = a0.y;
    As[acol + 2][arow] = a0.z; As[acol + 3][arow] = a0.w;
    As[acol + 0][arow + 64] = a1.x; As[acol + 1][arow + 64] = a1.y;
    As[acol + 2][arow + 64] = a1.z; As[acol + 3][arow + 64] = a1.w;
    *(float4*)&Bs[brow][bcol]     = b0;
    *(float4*)&Bs[brow + 8][bcol] = b1;
    __syncthreads();
#pragma unroll
    for (int kk = 0; kk < BK; ++kk) {
      float a[8], bb[8];
      float4 t;
      t = *(float4*)&As[kk][ty * 8];     a[0]=t.x; a[1]=t.y; a[2]=t.z; a[3]=t.w;
      t = *(float4*)&As[kk][ty * 8 + 4]; a[4]=t.x; a[5]=t.y; a[6]=t.z; a[7]=t.w;
      t = *(float4*)&Bs[kk][tx * 8];     bb[0]=t.x; bb[1]=t.y; bb[2]=t.z; bb[3]=t.w;
      t = *(float4*)&Bs[kk][tx * 8 + 4]; bb[4]=t.x; bb[5]=t.y; bb[6]=t.z; bb[7]=t.w;
#pragma unroll
      for (int i = 0; i < 8; ++i)
#pragma unroll
        for (int j = 0; j < 8; ++j)
          acc[i][j] = fmaf(a[i], bb[j], acc[i][j]);
    }
  }

  const float4 bias0 = *(const float4*)(bias + bn + tx * 8);
  const float4 bias1 = *(const float4*)(bias + bn + tx * 8 + 4);
  if (mode == 0) {
#pragma unroll
    for (int i = 0; i < 8; ++i) {
      const int m = bm + ty * 8 + i;
      float* dst = C + (size_t)m * 1024 + bn + tx * 8;
      *(float4*)dst = make_float4(acc[i][0] + bias0.x, acc[i][1] + bias0.y,
                                  acc[i][2] + bias0.z, acc[i][3] + bias0.w);
      *(float4*)(dst + 4) = make_float4(acc[i][4] + bias1.x, acc[i][5] + bias1.y,
                                        acc[i][6] + bias1.z, acc[i][7] + bias1.w);
    }
  } else {
    const int ncol = bn + tx * 8;
    const int h  = ncol >> 6;
    const int dk = ncol & 63;
#pragma unroll
    for (int i = 0; i < 8; ++i) {
      const int m = bm + ty * 8 + i;
      const int bb2 = m >> 11;
      const int s  = m & 2047;
      float* dst = C + ((size_t)(bb2 * H_ + h) * S_ + s) * DK_ + dk;
      *(float4*)dst = make_float4(acc[i][0] + bias0.x, acc[i][1] + bias0.y,
                                  acc[i][2] + bias0.z, acc[i][3] + bias0.w);
      *(float4*)(dst + 4) = make_float4(acc[i][4] + bias1.x, acc[i][5] + bias1.y,
                                        acc[i][6] + bias1.z, acc[i][7] + bias1.w);
    }
  }
}

__global__ __launch_bounds__(256, 2) void attn_v3(
    const float* __restrict__ Qp, const float* __restrict__ Kp,
    const float* __restrict__ Vp, const float* __restrict__ amask,
    float* __restrict__ AO)
{
  __shared__ float Qs[64][68], Ks[64][68], Vs[64][68], Ps[64][68];

  const int tid = threadIdx.x;
  const int qt = blockIdx.x;
  const int h  = blockIdx.y;
  const int b  = blockIdx.z;
  const int i0 = qt * 64;
  const int tr = tid >> 4;
  const int tc = tid & 15;

  const size_t head_off = (size_t)(b * H_ + h) * S_ * DK_;
  const float* Qh = Qp + head_off;
  const float* Kh = Kp + head_off;
  const float* Vh = Vp + head_off;

#pragma unroll
  for (int r = 0; r < 4; ++r) {
    const int f = tid + r * 256;
    const int row = f >> 4, col = (f & 15) * 4;
    *(float4*)&Qs[row][col] = *(const float4*)(Qh + (size_t)(i0 + row) * DK_ + col);
  }

  float m_i[4], l_i[4];
  float4 acc[4];
#pragma unroll
  for (int i = 0; i < 4; ++i) {
    m_i[i] = -1e30f; l_i[i] = 0.f;
    acc[i] = make_float4(0.f, 0.f, 0.f, 0.f);
  }

  int start, t_lo, t_hi;
  if (qt == 0) { start = 0; t_lo = 0; t_hi = 31; }
  else {
    start = -1;
    t_lo = qt - 4 < 1 ? 1 : qt - 4;
    t_hi = qt + 4 > 31 ? 31 : qt + 4;
  }

  for (int tt = start; tt <= t_hi; ++tt) {
    if (tt >= 0 && tt < t_lo) continue;
    const int kt = (tt < 0) ? 0 : tt;
    const int k0 = kt * 64;

    __syncthreads();
#pragma unroll
    for (int r = 0; r < 4; ++r) {
      const int f = tid + r * 256;
      const int row = f >> 4, col = (f & 15) * 4;
      *(float4*)&Ks[row][col] = *(const float4*)(Kh + (size_t)(k0 + row) * DK_ + col);
      *(float4*)&Vs[row][col] = *(const float4*)(Vh + (size_t)(k0 + row) * DK_ + col);
    }
    __syncthreads();

    float am[4];
#pragma unroll
    for (int u = 0; u < 4; ++u) am[u] = amask[b * S_ + k0 + tc + 16 * u];

    float s[4][4];
#pragma unroll
    for (int i = 0; i < 4; ++i)
#pragma unroll
      for (int u = 0; u < 4; ++u) s[i][u] = 0.f;
#pragma unroll
    for (int d4 = 0; d4 < 16; ++d4) {
      const float4 k0v = *(float4*)&Ks[tc     ][d4 * 4];
      const float4 k1v = *(float4*)&Ks[tc + 16][d4 * 4];
      const float4 k2v = *(float4*)&Ks[tc + 32][d4 * 4];
      const float4 k3v = *(float4*)&Ks[tc + 48][d4 * 4];
#pragma unroll
      for (int i = 0; i < 4; ++i) {
        const float4 q = *(float4*)&Qs[tr * 4 + i][d4 * 4];
        s[i][0] += q.x*k0v.x + q.y*k0v.y + q.z*k0v.z + q.w*k0v.w;
        s[i][1] += q.x*k1v.x + q.y*k1v.y + q.z*k1v.z + q.w*k1v.w;
        s[i][2] += q.x*k2v.x + q.y*k2v.y + q.z*k2v.z + q.w*k2v.w;
        s[i][3] += q.x*k3v.x + q.y*k3v.y + q.z*k3v.z + q.w*k3v.w;
      }
    }

#pragma unroll
    for (int i = 0; i < 4; ++i) {
      const int irow = i0 + tr * 4 + i;
#pragma unroll
      for (int u = 0; u < 4; ++u) {
        const int j = k0 + tc + 16 * u;
        const int diff = irow - j;
        const bool allowed = (diff <= WIN_ && diff >= -WIN_) || (irow < GLB_) || (j < GLB_);
        s[i][u] = allowed ? fmaf(s[i][u], 0.125f, am[u]) : -1e30f;
      }
    }

    float mt[4];
#pragma unroll
    for (int i = 0; i < 4; ++i)
      mt[i] = fmaxf(fmaxf(s[i][0], s[i][1]), fmaxf(s[i][2], s[i][3]));
#pragma unroll
    for (int st = 1; st <= 8; st <<= 1)
#pragma unroll
      for (int i = 0; i < 4; ++i)
        mt[i] = fmaxf(mt[i], __shfl_xor(mt[i], st));

    float alpha[4], rs[4];
#pragma unroll
    for (int i = 0; i < 4; ++i) {
      const float mn = fmaxf(m_i[i], mt[i]);
      alpha[i] = __expf(m_i[i] - mn);
      m_i[i] = mn;
      float r = 0.f;
#pragma unroll
      for (int u = 0; u < 4; ++u) {
        s[i][u] = __expf(s[i][u] - mn);
        r += s[i][u];
      }
      rs[i] = r;
    }
#pragma unroll
    for (int st = 1; st <= 8; st <<= 1)
#pragma unroll
      for (int i = 0; i < 4; ++i)
        rs[i] += __shfl_xor(rs[i], st);
#pragma unroll
    for (int i = 0; i < 4; ++i) {
      l_i[i] = l_i[i] * alpha[i] + rs[i];
      acc[i].x *= alpha[i]; acc[i].y *= alpha[i];
      acc[i].z *= alpha[i]; acc[i].w *= alpha[i];
    }

#pragma unroll
    for (int u = 0; u < 4; ++u)
      *(float4*)&Ps[tc + 16 * u][tr * 4] =
          make_float4(s[0][u], s[1][u], s[2][u], s[3][u]);
    __syncthreads();

#pragma unroll 4
    for (int j = 0; j < 64; ++j) {
      const float4 p4 = *(float4*)&Ps[j][tr * 4];
      const float4 v4 = *(float4*)&Vs[j][tc * 4];
      acc[0].x = fmaf(p4.x, v4.x, acc[0].x); acc[0].y = fmaf(p4.x, v4.y, acc[0].y);
      acc[0].z = fmaf(p4.x, v4.z, acc[0].z); acc[0].w = fmaf(p4.x, v4.w, acc[0].w);
      acc[1].x = fmaf(p4.y, v4.x, acc[1].x); acc[1].y = fmaf(p4.y, v4.y, acc[1].y);
      acc[1].z = fmaf(p4.y, v4.z, acc[1].z); acc[1].w = fmaf(p4.y, v4.w, acc[1].w);
      acc[2].x = fmaf(p4.z, v4.x, acc[2].x); acc[2].y = fmaf(p4.z, v4.y, acc[2].y);
      acc[2].z = fmaf(p4.z, v4.z, acc[2].z); acc[2].w = fmaf(p4.z, v4.w, acc[2].w);
      acc[3].x = fmaf(p4.w, v4.x, acc[3].x); acc[3].y = fmaf(p4.w, v4.y, acc[3].y);
      acc[3].z = fmaf(p4.w, v4.z, acc[3].z); acc[3].w = fmaf(p4.w, v4.w, acc[3].w);
    }
  }

#pragma unroll
  for (int i = 0; i < 4; ++i) {
    const float linv = 1.0f / l_i[i];
    const int row = i0 + tr * 4 + i;
    float* dst = AO + ((size_t)b * S_ + row) * D_ + h * DK_ + tc * 4;
    *(float4*)dst = make_float4(acc[i].x * linv, acc[i].y * linv,
                                acc[i].z * linv, acc[i].w * linv);
  }
}

// ---------------------------------------------------------------------------
extern "C" void kernel_launch(void* const* d_in, const int* in_sizes, int n_in,
                              void* d_out, int out_size, void* d_ws, size_t ws_size,
                              hipStream_t stream) {
  const float* q  = (const float*)d_in[0];
  const float* k  = (const float*)d_in[1];
  const float* v  = (const float*)d_in[2];
  const float* am = (const float*)d_in[3];
  const float* wq = (const float*)d_in[4];
  const float* bq = (const float*)d_in[5];
  const float* wk = (const float*)d_in[6];
  const float* bk = (const float*)d_in[7];
  const float* wv = (const float*)d_in[8];
  const float* bv = (const float*)d_in[9];
  const float* wo = (const float*)d_in[10];
  const float* bo = (const float*)d_in[11];
  float* out = (float*)d_out;

  const size_t PER = (size_t)B_ * H_ * S_ * DK_;   // 8,388,608 elements
  const size_t NEED = 138412032;

  if (ws_size >= NEED) {
    unsigned short* us = (unsigned short*)d_ws;
    unsigned short* ACTh = us;                  // also AOhi after attn
    unsigned short* ACTl = us + PER;            // also AOlo
    unsigned short* Qhi  = us + 2 * PER;
    unsigned short* Qlo  = us + 3 * PER;
    unsigned short* Khi  = us + 4 * PER;
    unsigned short* Klo  = us + 5 * PER;
    unsigned short* Vtp  = us + 6 * PER;
    unsigned short* WHI  = us + 7 * PER;
    unsigned short* WLO  = WHI + 1048576;

    const int sgrid = (int)(PER / 4 / 256);
    dim3 wgrid(32, 32);
    dim3 ggrid(8, 64);

    split_bf16<<<sgrid, 256, 0, stream>>>(q, ACTh, ACTl);
    wtsplit<<<wgrid, 256, 0, stream>>>(wq, WHI, WLO);
    gemm_mfma<<<ggrid, 256, 0, stream>>>(ACTh, ACTl, WHI, WLO, bq, nullptr, Qhi, Qlo, 1);

    split_bf16<<<sgrid, 256, 0, stream>>>(k, ACTh, ACTl);
    wtsplit<<<wgrid, 256, 0, stream>>>(wk, WHI, WLO);
    gemm_mfma<<<ggrid, 256, 0, stream>>>(ACTh, ACTl, WHI, WLO, bk, nullptr, Khi, Klo, 1);

    split_bf16<<<sgrid, 256, 0, stream>>>(v, ACTh, ACTl);
    wtsplit<<<wgrid, 256, 0, stream>>>(wv, WHI, WLO);
    gemm_mfma<<<ggrid, 256, 0, stream>>>(ACTh, ACTl, WHI, WLO, bv, nullptr, Vtp, nullptr, 2);

    attn_mfma<<<dim3(S_ / 64, H_, B_), 256, 0, stream>>>(
        Qhi, Qlo, Khi, Klo, Vtp, am, ACTh, ACTl);

    wtsplit<<<wgrid, 256, 0, stream>>>(wo, WHI, WLO);
    gemm_mfma<<<ggrid, 256, 0, stream>>>(ACTh, ACTl, WHI, WLO, bo, out, nullptr, nullptr, 0);
  } else {
    float* Qp = (float*)d_ws;
    float* Kp = Qp + PER;
    float* Vp = Kp + PER;
    float* AOf = Vp + PER;
    dim3 gg(D_ / BN, (B_ * S_) / BM);
    gemm_f32<<<gg, 256, 0, stream>>>(q, wq, bq, Qp, 1);
    gemm_f32<<<gg, 256, 0, stream>>>(k, wk, bk, Kp, 1);
    gemm_f32<<<gg, 256, 0, stream>>>(v, wv, bv, Vp, 1);
    attn_v3<<<dim3(S_ / 64, H_, B_), 256, 0, stream>>>(Qp, Kp, Vp, am, AOf);
    gemm_f32<<<gg, 256, 0, stream>>>(AOf, wo, bo, out, 0);
  }
}